// Round 3
// baseline (102.235 us; speedup 1.0000x reference)
//
#include <hip/hip_runtime.h>

#define NB 16
#define NN 256
#define NH 128
#define NE 16

typedef float v4f __attribute__((ext_vector_type(4)));

constexpr long long EF_ELEMS = (long long)NB * NN * NN * NE; // 16777216

// ws layout (floats): bps[16] | albe[17*68] | Pi[4096*32] | Pj[4096*32] | pooled[4096*16]

// ==================== prep: piecewise-linear fold of the dist MLP ====================
// t_k(d) = relu(dW1[k]*d + db1[k]);  dist contribution to pre-LN = t @ M + c2
// where M[k][c] = sum_e dW2[k][e]*uW1[256+e][c], c2[c] = ub1[c] + sum_e db2[e]*uW1[256+e][c].
// t@M + c2 is piecewise-linear in d: for each of 17 segments store alpha[c], beta[c]
// (beta includes c2). Runtime: seg = #breakpoints < d; contrib = alpha*d + beta.
__global__ __launch_bounds__(576) void k_prep2(
    const float* __restrict__ dW1, const float* __restrict__ db1,
    const float* __restrict__ dW2, const float* __restrict__ db2,
    const float* __restrict__ uW1, const float* __restrict__ ub1,
    float* __restrict__ bps, float* __restrict__ albe)
{
    __shared__ float sM[512];      // M[16][32]
    __shared__ float sBp[16];      // sorted breakpoints
    __shared__ float sA[16], sB[16];
    const int t = threadIdx.x;
    if (t < 512) {
        const int k = t >> 5, c = t & 31;
        float s = 0.f;
#pragma unroll
        for (int e = 0; e < 16; ++e)
            s = fmaf(dW2[k * 16 + e], uW1[(256 + e) * 32 + c], s);
        sM[t] = s;
    }
    if (t < 16) { sA[t] = dW1[t]; sB[t] = db1[t]; }
    __syncthreads();
    if (t < 16) {
        const float a = sA[t];
        const float x = (a != 0.f) ? (-sB[t] / a) : -1e30f;
        int r = 0;
        for (int q = 0; q < 16; ++q) {
            const float aq = sA[q];
            const float xq = (aq != 0.f) ? (-sB[q] / aq) : -1e30f;
            r += (xq < x) || (xq == x && q < t);
        }
        sBp[r] = x;
    }
    __syncthreads();
    if (t < 16) bps[t] = sBp[t];
    if (t < 544) {
        const int s = t >> 5, c = t & 31;
        float dt;
        if (s == 0)       dt = sBp[0] - 1.0f;
        else if (s == 16) dt = sBp[15] + 1.0f;
        else              dt = 0.5f * (sBp[s - 1] + sBp[s]);
        float alpha = 0.f, beta = 0.f;
#pragma unroll
        for (int k = 0; k < 16; ++k) {
            const bool act = fmaf(sA[k], dt, sB[k]) > 0.f;
            if (act) {
                const float m = sM[k * 32 + c];
                alpha = fmaf(sA[k], m, alpha);
                beta  = fmaf(sB[k], m, beta);
            }
        }
        float c2 = ub1[c];
#pragma unroll
        for (int e = 0; e < 16; ++e)
            c2 = fmaf(db2[e], uW1[(256 + e) * 32 + c], c2);
        albe[s * 68 + c]      = alpha;
        albe[s * 68 + 32 + c] = beta + c2;
    }
}

// ==================== proj: Pi = node @ uW1[:128], Pj = node @ uW1[128:256] ==========
__global__ __launch_bounds__(64) void k_proj(
    const float* __restrict__ node, const float* __restrict__ uW1,
    float* __restrict__ Pi, float* __restrict__ Pj)
{
    const int row = blockIdx.x;           // b*N + n  (4096 rows)
    const int tid = threadIdx.x;          // 64 threads
    __shared__ float nrow[128];
    nrow[tid]      = node[(size_t)row * 128 + tid];
    nrow[tid + 64] = node[(size_t)row * 128 + 64 + tid];
    __syncthreads();
    const int c = tid & 31;
    const int half = tid >> 5;            // 0 -> Pi, 1 -> Pj
    const float* w = uW1 + half * 128 * 32 + c;
    float s = 0.f;
#pragma unroll 8
    for (int k = 0; k < 128; ++k)
        s = fmaf(nrow[k], w[k * 32], s);
    (half ? Pj : Pi)[(size_t)row * 32 + c] = s;
}

// ==================== edge kernel =====================================================
__global__ __launch_bounds__(256) void k_edge2(
    const float* __restrict__ dist, const int* __restrict__ visited,
    const float* __restrict__ ln_g, const float* __restrict__ ln_b,
    const float* __restrict__ uW2, const float* __restrict__ ub2,
    const float* __restrict__ bps, const float* __restrict__ albe_g,
    const float* __restrict__ Pi, const float* __restrict__ Pj,
    float* __restrict__ ef_out, float* __restrict__ pooled)
{
    const int row = blockIdx.x;           // b*N + i
    const int b = row >> 8;
    const int j = threadIdx.x;

    __shared__ float albe[17 * 68];       // 4624 B, seg stride 68 floats (bank-spread)
    __shared__ float red[64][20];         // 5120 B, partial sums

    for (int q = j; q < 17 * 68; q += 256) albe[q] = albe_g[q];

    const float d = dist[(size_t)row * NN + j];

    // issue Pj loads early
    const float4* pj4 = reinterpret_cast<const float4*>(Pj + ((size_t)(b * NN + j)) * 32);
    float4 pj[8];
#pragma unroll
    for (int q = 0; q < 8; ++q) pj[q] = pj4[q];

    __syncthreads();

    // segment lookup: count breakpoints strictly below d
    int seg = 0;
#pragma unroll
    for (int k = 0; k < 16; ++k) seg += (d > bps[k]) ? 1 : 0;
    const float* ab = &albe[seg * 68];

    // pre[c] = Pi[row][c] + Pj[b,j][c] + d*alpha[c] + beta[c]
    const float* PiRow = Pi + (size_t)row * 32;    // uniform -> s_load
    float pre[32];
#pragma unroll
    for (int q = 0; q < 8; ++q) {
        const float4 al = *reinterpret_cast<const float4*>(&ab[q * 4]);
        const float4 be = *reinterpret_cast<const float4*>(&ab[32 + q * 4]);
        pre[q * 4 + 0] = PiRow[q * 4 + 0] + pj[q].x + fmaf(d, al.x, be.x);
        pre[q * 4 + 1] = PiRow[q * 4 + 1] + pj[q].y + fmaf(d, al.y, be.y);
        pre[q * 4 + 2] = PiRow[q * 4 + 2] + pj[q].z + fmaf(d, al.z, be.z);
        pre[q * 4 + 3] = PiRow[q * 4 + 3] + pj[q].w + fmaf(d, al.w, be.w);
    }

    // LayerNorm over 32 channels (4-way trees)
    float s0 = 0.f, s1 = 0.f, s2 = 0.f, s3 = 0.f;
#pragma unroll
    for (int c = 0; c < 32; c += 4) { s0 += pre[c]; s1 += pre[c + 1]; s2 += pre[c + 2]; s3 += pre[c + 3]; }
    const float mu = ((s0 + s1) + (s2 + s3)) * (1.f / 32.f);
    float v0 = 0.f, v1 = 0.f, v2 = 0.f, v3 = 0.f;
#pragma unroll
    for (int c = 0; c < 32; c += 4) {
        pre[c]     -= mu; v0 = fmaf(pre[c],     pre[c],     v0);
        pre[c + 1] -= mu; v1 = fmaf(pre[c + 1], pre[c + 1], v1);
        pre[c + 2] -= mu; v2 = fmaf(pre[c + 2], pre[c + 2], v2);
        pre[c + 3] -= mu; v3 = fmaf(pre[c + 3], pre[c + 3], v3);
    }
    const float rstd = rsqrtf(fmaf((v0 + v1) + (v2 + v3), 1.f / 32.f, 1e-5f));

    // relu(LN) @ uW2, fused per channel (no hc array)
    float ef[16];
#pragma unroll
    for (int e = 0; e < 16; ++e) ef[e] = ub2[e];
#pragma unroll
    for (int c = 0; c < 32; ++c) {
        const float h = fmaxf(fmaf(pre[c] * rstd, ln_g[c], ln_b[c]), 0.f);
#pragma unroll
        for (int e = 0; e < 16; ++e)
            ef[e] = fmaf(h, uW2[c * 16 + e], ef[e]);   // uniform -> s_load
    }

    const float scale = visited[row] ? 0.5f : 1.0f;    // uniform
#pragma unroll
    for (int e = 0; e < 16; ++e) ef[e] *= scale;

    // streaming write of edge_features (nontemporal, native vector type)
    v4f* op = reinterpret_cast<v4f*>(ef_out + ((size_t)row * NN + j) * 16);
    __builtin_nontemporal_store((v4f){ef[0],  ef[1],  ef[2],  ef[3]},  op + 0);
    __builtin_nontemporal_store((v4f){ef[4],  ef[5],  ef[6],  ef[7]},  op + 1);
    __builtin_nontemporal_store((v4f){ef[8],  ef[9],  ef[10], ef[11]}, op + 2);
    __builtin_nontemporal_store((v4f){ef[12], ef[13], ef[14], ef[15]}, op + 3);

    // pooled mean: 2-level lane fold, then LDS finish
#pragma unroll
    for (int e = 0; e < 16; ++e) {
        float v = ef[e];
        v += __shfl_xor(v, 32);
        v += __shfl_xor(v, 16);
        ef[e] = v;
    }
    const int lane = j & 63, wave = j >> 6;
    if (lane < 16) {
        float* r = &red[wave * 16 + lane][0];
        *reinterpret_cast<v4f*>(r + 0)  = (v4f){ef[0],  ef[1],  ef[2],  ef[3]};
        *reinterpret_cast<v4f*>(r + 4)  = (v4f){ef[4],  ef[5],  ef[6],  ef[7]};
        *reinterpret_cast<v4f*>(r + 8)  = (v4f){ef[8],  ef[9],  ef[10], ef[11]};
        *reinterpret_cast<v4f*>(r + 12) = (v4f){ef[12], ef[13], ef[14], ef[15]};
    }
    __syncthreads();
    if (j < 64) {
        const int e = j & 15, g = j >> 4;
        float s = 0.f;
#pragma unroll
        for (int v = 0; v < 16; ++v) s += red[g * 16 + v][e];
        s += __shfl_down(s, 32);
        s += __shfl_down(s, 16);
        if (j < 16) pooled[(size_t)row * 16 + j] = s * (1.f / 256.f);
    }
}

// ==================== node MLP =======================================================
__global__ __launch_bounds__(128) void k_node(
    const float* __restrict__ pooled,
    const float* __restrict__ nW1, const float* __restrict__ nb1,
    const float* __restrict__ nW2, const float* __restrict__ nb2,
    float* __restrict__ msg_out)
{
    const int row = blockIdx.x;           // b*N + n
    const int tid = threadIdx.x;          // 128 threads
    __shared__ float hid[64];
    __shared__ float prow[16];
    if (tid < 16) prow[tid] = pooled[(size_t)row * 16 + tid];
    __syncthreads();
    if (tid < 64) {
        float s = nb1[tid];
#pragma unroll
        for (int e = 0; e < 16; ++e)
            s = fmaf(prow[e], nW1[e * 64 + tid], s);
        hid[tid] = fmaxf(s, 0.f);
    }
    __syncthreads();
    float s = nb2[tid];
#pragma unroll 8
    for (int q = 0; q < 64; ++q)
        s = fmaf(hid[q], nW2[q * 128 + tid], s);
    msg_out[(size_t)row * 128 + tid] = s;
}

extern "C" void kernel_launch(void* const* d_in, const int* in_sizes, int n_in,
                              void* d_out, int out_size, void* d_ws, size_t ws_size,
                              hipStream_t stream)
{
    const float* node    = (const float*)d_in[0];
    const float* dist    = (const float*)d_in[1];
    const int*   visited = (const int*)  d_in[2];
    const float* dW1     = (const float*)d_in[3];
    const float* db1     = (const float*)d_in[4];
    const float* dW2     = (const float*)d_in[5];
    const float* db2     = (const float*)d_in[6];
    const float* uW1     = (const float*)d_in[7];
    const float* ub1     = (const float*)d_in[8];
    const float* ln_g    = (const float*)d_in[9];
    const float* ln_b    = (const float*)d_in[10];
    const float* uW2     = (const float*)d_in[11];
    const float* ub2     = (const float*)d_in[12];
    const float* nW1     = (const float*)d_in[13];
    const float* nb1     = (const float*)d_in[14];
    const float* nW2     = (const float*)d_in[15];
    const float* nb2     = (const float*)d_in[16];

    float* ws     = (float*)d_ws;
    float* bps    = ws;                    // 16
    float* albe   = ws + 16;               // 17*68 = 1156
    float* Pi     = ws + 16 + 1156;        // 4096*32
    float* Pj     = Pi + 4096 * 32;        // 4096*32
    float* pooled = Pj + 4096 * 32;        // 4096*16

    float* out = (float*)d_out;
    float* msg = out + EF_ELEMS;

    hipLaunchKernelGGL(k_prep2, dim3(1), dim3(576), 0, stream,
                       dW1, db1, dW2, db2, uW1, ub1, bps, albe);
    hipLaunchKernelGGL(k_proj, dim3(NB * NN), dim3(64), 0, stream, node, uW1, Pi, Pj);
    hipLaunchKernelGGL(k_edge2, dim3(NB * NN), dim3(256), 0, stream,
                       dist, visited, ln_g, ln_b, uW2, ub2, bps, albe, Pi, Pj, out, pooled);
    hipLaunchKernelGGL(k_node, dim3(NB * NN), dim3(128), 0, stream, pooled, nW1, nb1, nW2, nb2, msg);
}

// Round 4
// 63.869 us; speedup vs baseline: 1.6007x; 1.6007x over previous
//
#include <hip/hip_runtime.h>

#define NB 16
#define NN 256
#define NH 128
#define NE 16

typedef float v4f __attribute__((ext_vector_type(4)));

constexpr long long EF_ELEMS = (long long)NB * NN * NN * NE; // 16777216

// ws layout (floats): bps[16] | albe[17*68] | Pi[4096*32] | Pj[4096*32] | pooled[4096*16]

// ==================== prep: piecewise-linear fold of the dist MLP ====================
// t_k(d) = relu(dW1[k]*d + db1[k]);  dist contribution to pre-LN = t @ M + c2
// where M[k][c] = sum_e dW2[k][e]*uW1[256+e][c], c2[c] = ub1[c] + sum_e db2[e]*uW1[256+e][c].
// t@M + c2 is piecewise-linear in d: for each of 17 segments store alpha[c], beta[c]
// (beta includes c2). Runtime: seg = #breakpoints < d; contrib = alpha*d + beta.
__global__ __launch_bounds__(576) void k_prep2(
    const float* __restrict__ dW1, const float* __restrict__ db1,
    const float* __restrict__ dW2, const float* __restrict__ db2,
    const float* __restrict__ uW1, const float* __restrict__ ub1,
    float* __restrict__ bps, float* __restrict__ albe)
{
    __shared__ float sM[512];      // M[16][32]
    __shared__ float sBp[16];      // sorted breakpoints
    __shared__ float sA[16], sB[16];
    const int t = threadIdx.x;
    if (t < 512) {
        const int k = t >> 5, c = t & 31;
        float s = 0.f;
#pragma unroll
        for (int e = 0; e < 16; ++e)
            s = fmaf(dW2[k * 16 + e], uW1[(256 + e) * 32 + c], s);
        sM[t] = s;
    }
    if (t < 16) { sA[t] = dW1[t]; sB[t] = db1[t]; }
    __syncthreads();
    if (t < 16) {
        const float a = sA[t];
        const float x = (a != 0.f) ? (-sB[t] / a) : -1e30f;
        int r = 0;
        for (int q = 0; q < 16; ++q) {
            const float aq = sA[q];
            const float xq = (aq != 0.f) ? (-sB[q] / aq) : -1e30f;
            r += (xq < x) || (xq == x && q < t);
        }
        sBp[r] = x;
    }
    __syncthreads();
    if (t < 16) bps[t] = sBp[t];
    if (t < 544) {
        const int s = t >> 5, c = t & 31;
        float dt;
        if (s == 0)       dt = sBp[0] - 1.0f;
        else if (s == 16) dt = sBp[15] + 1.0f;
        else              dt = 0.5f * (sBp[s - 1] + sBp[s]);
        float alpha = 0.f, beta = 0.f;
#pragma unroll
        for (int k = 0; k < 16; ++k) {
            const bool act = fmaf(sA[k], dt, sB[k]) > 0.f;
            if (act) {
                const float m = sM[k * 32 + c];
                alpha = fmaf(sA[k], m, alpha);
                beta  = fmaf(sB[k], m, beta);
            }
        }
        float c2 = ub1[c];
#pragma unroll
        for (int e = 0; e < 16; ++e)
            c2 = fmaf(db2[e], uW1[(256 + e) * 32 + c], c2);
        albe[s * 68 + c]      = alpha;
        albe[s * 68 + 32 + c] = beta + c2;
    }
}

// ==================== proj: Pi = node @ uW1[:128], Pj = node @ uW1[128:256] ==========
__global__ __launch_bounds__(64) void k_proj(
    const float* __restrict__ node, const float* __restrict__ uW1,
    float* __restrict__ Pi, float* __restrict__ Pj)
{
    const int row = blockIdx.x;           // b*N + n  (4096 rows)
    const int tid = threadIdx.x;          // 64 threads
    __shared__ float nrow[128];
    nrow[tid]      = node[(size_t)row * 128 + tid];
    nrow[tid + 64] = node[(size_t)row * 128 + 64 + tid];
    __syncthreads();
    const int c = tid & 31;
    const int half = tid >> 5;            // 0 -> Pi, 1 -> Pj
    const float* w = uW1 + half * 128 * 32 + c;
    float s = 0.f;
#pragma unroll 8
    for (int k = 0; k < 128; ++k)
        s = fmaf(nrow[k], w[k * 32], s);
    (half ? Pj : Pi)[(size_t)row * 32 + c] = s;
}

// ==================== edge kernel =====================================================
__global__ __launch_bounds__(256) void k_edge2(
    const float* __restrict__ dist, const int* __restrict__ visited,
    const float* __restrict__ ln_g, const float* __restrict__ ln_b,
    const float* __restrict__ uW2, const float* __restrict__ ub2,
    const float* __restrict__ bps, const float* __restrict__ albe_g,
    const float* __restrict__ Pi, const float* __restrict__ Pj,
    float* __restrict__ ef_out, float* __restrict__ pooled)
{
    const int row = blockIdx.x;           // b*N + i
    const int b = row >> 8;
    const int j = threadIdx.x;

    __shared__ float albe[17 * 68];       // 4624 B, seg stride 68 floats (bank-spread)
    __shared__ float red[64][20];         // 5120 B, partial sums

    for (int q = j; q < 17 * 68; q += 256) albe[q] = albe_g[q];

    const float d = dist[(size_t)row * NN + j];

    // issue Pj loads early
    const float4* pj4 = reinterpret_cast<const float4*>(Pj + ((size_t)(b * NN + j)) * 32);
    float4 pj[8];
#pragma unroll
    for (int q = 0; q < 8; ++q) pj[q] = pj4[q];

    __syncthreads();

    // segment lookup: count breakpoints strictly below d
    int seg = 0;
#pragma unroll
    for (int k = 0; k < 16; ++k) seg += (d > bps[k]) ? 1 : 0;
    const float* ab = &albe[seg * 68];

    // pre[c] = Pi[row][c] + Pj[b,j][c] + d*alpha[c] + beta[c]
    const float* PiRow = Pi + (size_t)row * 32;    // uniform -> s_load
    float pre[32];
#pragma unroll
    for (int q = 0; q < 8; ++q) {
        const float4 al = *reinterpret_cast<const float4*>(&ab[q * 4]);
        const float4 be = *reinterpret_cast<const float4*>(&ab[32 + q * 4]);
        pre[q * 4 + 0] = PiRow[q * 4 + 0] + pj[q].x + fmaf(d, al.x, be.x);
        pre[q * 4 + 1] = PiRow[q * 4 + 1] + pj[q].y + fmaf(d, al.y, be.y);
        pre[q * 4 + 2] = PiRow[q * 4 + 2] + pj[q].z + fmaf(d, al.z, be.z);
        pre[q * 4 + 3] = PiRow[q * 4 + 3] + pj[q].w + fmaf(d, al.w, be.w);
    }

    // LayerNorm over 32 channels (4-way trees)
    float s0 = 0.f, s1 = 0.f, s2 = 0.f, s3 = 0.f;
#pragma unroll
    for (int c = 0; c < 32; c += 4) { s0 += pre[c]; s1 += pre[c + 1]; s2 += pre[c + 2]; s3 += pre[c + 3]; }
    const float mu = ((s0 + s1) + (s2 + s3)) * (1.f / 32.f);
    float v0 = 0.f, v1 = 0.f, v2 = 0.f, v3 = 0.f;
#pragma unroll
    for (int c = 0; c < 32; c += 4) {
        pre[c]     -= mu; v0 = fmaf(pre[c],     pre[c],     v0);
        pre[c + 1] -= mu; v1 = fmaf(pre[c + 1], pre[c + 1], v1);
        pre[c + 2] -= mu; v2 = fmaf(pre[c + 2], pre[c + 2], v2);
        pre[c + 3] -= mu; v3 = fmaf(pre[c + 3], pre[c + 3], v3);
    }
    const float rstd = rsqrtf(fmaf((v0 + v1) + (v2 + v3), 1.f / 32.f, 1e-5f));

    // relu(LN) @ uW2, fused per channel (no hc array)
    float ef[16];
#pragma unroll
    for (int e = 0; e < 16; ++e) ef[e] = ub2[e];
#pragma unroll
    for (int c = 0; c < 32; ++c) {
        const float h = fmaxf(fmaf(pre[c] * rstd, ln_g[c], ln_b[c]), 0.f);
#pragma unroll
        for (int e = 0; e < 16; ++e)
            ef[e] = fmaf(h, uW2[c * 16 + e], ef[e]);   // uniform -> s_load
    }

    const float scale = visited[row] ? 0.5f : 1.0f;    // uniform
#pragma unroll
    for (int e = 0; e < 16; ++e) ef[e] *= scale;

    // write edge_features (regular stores: L2 assembles full lines, ~exact 67 MB writeback)
    float4* op = reinterpret_cast<float4*>(ef_out + ((size_t)row * NN + j) * 16);
    op[0] = make_float4(ef[0],  ef[1],  ef[2],  ef[3]);
    op[1] = make_float4(ef[4],  ef[5],  ef[6],  ef[7]);
    op[2] = make_float4(ef[8],  ef[9],  ef[10], ef[11]);
    op[3] = make_float4(ef[12], ef[13], ef[14], ef[15]);

    // pooled mean: 2-level lane fold, then LDS finish
#pragma unroll
    for (int e = 0; e < 16; ++e) {
        float v = ef[e];
        v += __shfl_xor(v, 32);
        v += __shfl_xor(v, 16);
        ef[e] = v;
    }
    const int lane = j & 63, wave = j >> 6;
    if (lane < 16) {
        float* r = &red[wave * 16 + lane][0];
        *reinterpret_cast<v4f*>(r + 0)  = (v4f){ef[0],  ef[1],  ef[2],  ef[3]};
        *reinterpret_cast<v4f*>(r + 4)  = (v4f){ef[4],  ef[5],  ef[6],  ef[7]};
        *reinterpret_cast<v4f*>(r + 8)  = (v4f){ef[8],  ef[9],  ef[10], ef[11]};
        *reinterpret_cast<v4f*>(r + 12) = (v4f){ef[12], ef[13], ef[14], ef[15]};
    }
    __syncthreads();
    if (j < 64) {
        const int e = j & 15, g = j >> 4;
        float s = 0.f;
#pragma unroll
        for (int v = 0; v < 16; ++v) s += red[g * 16 + v][e];
        s += __shfl_down(s, 32);
        s += __shfl_down(s, 16);
        if (j < 16) pooled[(size_t)row * 16 + j] = s * (1.f / 256.f);
    }
}

// ==================== node MLP =======================================================
__global__ __launch_bounds__(128) void k_node(
    const float* __restrict__ pooled,
    const float* __restrict__ nW1, const float* __restrict__ nb1,
    const float* __restrict__ nW2, const float* __restrict__ nb2,
    float* __restrict__ msg_out)
{
    const int row = blockIdx.x;           // b*N + n
    const int tid = threadIdx.x;          // 128 threads
    __shared__ float hid[64];
    __shared__ float prow[16];
    if (tid < 16) prow[tid] = pooled[(size_t)row * 16 + tid];
    __syncthreads();
    if (tid < 64) {
        float s = nb1[tid];
#pragma unroll
        for (int e = 0; e < 16; ++e)
            s = fmaf(prow[e], nW1[e * 64 + tid], s);
        hid[tid] = fmaxf(s, 0.f);
    }
    __syncthreads();
    float s = nb2[tid];
#pragma unroll 8
    for (int q = 0; q < 64; ++q)
        s = fmaf(hid[q], nW2[q * 128 + tid], s);
    msg_out[(size_t)row * 128 + tid] = s;
}

extern "C" void kernel_launch(void* const* d_in, const int* in_sizes, int n_in,
                              void* d_out, int out_size, void* d_ws, size_t ws_size,
                              hipStream_t stream)
{
    const float* node    = (const float*)d_in[0];
    const float* dist    = (const float*)d_in[1];
    const int*   visited = (const int*)  d_in[2];
    const float* dW1     = (const float*)d_in[3];
    const float* db1     = (const float*)d_in[4];
    const float* dW2     = (const float*)d_in[5];
    const float* db2     = (const float*)d_in[6];
    const float* uW1     = (const float*)d_in[7];
    const float* ub1     = (const float*)d_in[8];
    const float* ln_g    = (const float*)d_in[9];
    const float* ln_b    = (const float*)d_in[10];
    const float* uW2     = (const float*)d_in[11];
    const float* ub2     = (const float*)d_in[12];
    const float* nW1     = (const float*)d_in[13];
    const float* nb1     = (const float*)d_in[14];
    const float* nW2     = (const float*)d_in[15];
    const float* nb2     = (const float*)d_in[16];

    float* ws     = (float*)d_ws;
    float* bps    = ws;                    // 16
    float* albe   = ws + 16;               // 17*68 = 1156
    float* Pi     = ws + 16 + 1156;        // 4096*32
    float* Pj     = Pi + 4096 * 32;        // 4096*32
    float* pooled = Pj + 4096 * 32;        // 4096*16

    float* out = (float*)d_out;
    float* msg = out + EF_ELEMS;

    hipLaunchKernelGGL(k_prep2, dim3(1), dim3(576), 0, stream,
                       dW1, db1, dW2, db2, uW1, ub1, bps, albe);
    hipLaunchKernelGGL(k_proj, dim3(NB * NN), dim3(64), 0, stream, node, uW1, Pi, Pj);
    hipLaunchKernelGGL(k_edge2, dim3(NB * NN), dim3(256), 0, stream,
                       dist, visited, ln_g, ln_b, uW2, ub2, bps, albe, Pi, Pj, out, pooled);
    hipLaunchKernelGGL(k_node, dim3(NB * NN), dim3(128), 0, stream, pooled, nW1, nb1, nW2, nb2, msg);
}

// Round 5
// 52.143 us; speedup vs baseline: 1.9607x; 1.2249x over previous
//
#include <hip/hip_runtime.h>

#define NB 16
#define NN 256
#define NH 128
#define NE 16

typedef float v4f  __attribute__((ext_vector_type(4)));
typedef short bf16x8 __attribute__((ext_vector_type(8)));
typedef unsigned int uint;

constexpr long long EF_ELEMS = (long long)NB * NN * NN * NE; // 16777216

// ws layout (floats): bps[16] | albe[17*68] | Pi[4096*32] | Pj[4096*32] | pooled[4096*16]

// ==================== prep: piecewise-linear fold of the dist MLP ====================
__global__ __launch_bounds__(576) void k_prep2(
    const float* __restrict__ dW1, const float* __restrict__ db1,
    const float* __restrict__ dW2, const float* __restrict__ db2,
    const float* __restrict__ uW1, const float* __restrict__ ub1,
    float* __restrict__ bps, float* __restrict__ albe)
{
    __shared__ float sM[512];      // M[16][32]
    __shared__ float sBp[16];      // sorted breakpoints
    __shared__ float sA[16], sB[16];
    const int t = threadIdx.x;
    if (t < 512) {
        const int k = t >> 5, c = t & 31;
        float s = 0.f;
#pragma unroll
        for (int e = 0; e < 16; ++e)
            s = fmaf(dW2[k * 16 + e], uW1[(256 + e) * 32 + c], s);
        sM[t] = s;
    }
    if (t < 16) { sA[t] = dW1[t]; sB[t] = db1[t]; }
    __syncthreads();
    if (t < 16) {
        const float a = sA[t];
        const float x = (a != 0.f) ? (-sB[t] / a) : -1e30f;
        int r = 0;
        for (int q = 0; q < 16; ++q) {
            const float aq = sA[q];
            const float xq = (aq != 0.f) ? (-sB[q] / aq) : -1e30f;
            r += (xq < x) || (xq == x && q < t);
        }
        sBp[r] = x;
    }
    __syncthreads();
    if (t < 16) bps[t] = sBp[t];
    if (t < 544) {
        const int s = t >> 5, c = t & 31;
        float dt;
        if (s == 0)       dt = sBp[0] - 1.0f;
        else if (s == 16) dt = sBp[15] + 1.0f;
        else              dt = 0.5f * (sBp[s - 1] + sBp[s]);
        float alpha = 0.f, beta = 0.f;
#pragma unroll
        for (int k = 0; k < 16; ++k) {
            const bool act = fmaf(sA[k], dt, sB[k]) > 0.f;
            if (act) {
                const float m = sM[k * 32 + c];
                alpha = fmaf(sA[k], m, alpha);
                beta  = fmaf(sB[k], m, beta);
            }
        }
        float c2 = ub1[c];
#pragma unroll
        for (int e = 0; e < 16; ++e)
            c2 = fmaf(db2[e], uW1[(256 + e) * 32 + c], c2);
        albe[s * 68 + c]      = alpha;
        albe[s * 68 + 32 + c] = beta + c2;
    }
}

// ==================== proj: Pi = node @ uW1[:128], Pj = node @ uW1[128:256] ==========
__global__ __launch_bounds__(64) void k_proj(
    const float* __restrict__ node, const float* __restrict__ uW1,
    float* __restrict__ Pi, float* __restrict__ Pj)
{
    const int row = blockIdx.x;           // b*N + n  (4096 rows)
    const int tid = threadIdx.x;          // 64 threads
    __shared__ float nrow[128];
    nrow[tid]      = node[(size_t)row * 128 + tid];
    nrow[tid + 64] = node[(size_t)row * 128 + 64 + tid];
    __syncthreads();
    const int c = tid & 31;
    const int half = tid >> 5;            // 0 -> Pi, 1 -> Pj
    const float* w = uW1 + half * 128 * 32 + c;
    float s = 0.f;
#pragma unroll 8
    for (int k = 0; k < 128; ++k)
        s = fmaf(nrow[k], w[k * 32], s);
    (half ? Pj : Pi)[(size_t)row * 32 + c] = s;
}

// ==================== edge kernel (MFMA epilogue) =====================================
// Per block: row i, 256 edges. Threads compute h[32] (pre-LN + LN + relu) in f32,
// pack to bf16 in LDS; each wave then does D[e][edge] = (uW2_hi + uW2_lo)^T @ h via
// 2 MFMA per 16-edge tile. K-slot pairing between A and B is consistent by
// construction: both sides packed with v_cvt_pk_bf16_f32(elem0, elem1) and the same
// (group,t)->channel map, so the HW's internal K permutation cancels.
__global__ __launch_bounds__(256) void k_edge3(
    const float* __restrict__ dist, const int* __restrict__ visited,
    const float* __restrict__ ln_g, const float* __restrict__ ln_b,
    const float* __restrict__ uW2, const float* __restrict__ ub2,
    const float* __restrict__ bps, const float* __restrict__ albe_g,
    const float* __restrict__ Pi, const float* __restrict__ Pj,
    float* __restrict__ ef_out, float* __restrict__ pooled)
{
    const int row = blockIdx.x;           // b*N + i
    const int b = row >> 8;
    const int j = threadIdx.x;

    __shared__ float albe[17 * 68];       // 4624 B
    __shared__ uint  h_lds[256 * 20];     // 20480 B: [edge][16 dwords bf16-pairs], pad 20
    __shared__ uint  w_hi_s[16 * 20];     // 1280 B: A-operand rows (e) x 16 dwords, pad 20
    __shared__ uint  w_lo_s[16 * 20];     // 1280 B
    __shared__ float red2[4][16];         // 256 B

    for (int q = j; q < 17 * 68; q += 256) albe[q] = albe_g[q];

    // stage uW2 as bf16 hi/lo split, A-layout [e][channel pairs]
    {
        const int e = j & 15, q = j >> 4;   // q in 0..15 -> channels 2q, 2q+1
        const float w0 = uW2[(2 * q) * 16 + e];
        const float w1 = uW2[(2 * q + 1) * 16 + e];
        uint W00, W11, Whi, Wlo;
        asm("v_cvt_pk_bf16_f32 %0, %1, %2" : "=v"(W00) : "v"(w0), "v"(w0));
        asm("v_cvt_pk_bf16_f32 %0, %1, %2" : "=v"(W11) : "v"(w1), "v"(w1));
        const float w0h = __uint_as_float(W00 << 16);  // bf16(w0) as f32 (position-agnostic)
        const float w1h = __uint_as_float(W11 << 16);
        asm("v_cvt_pk_bf16_f32 %0, %1, %2" : "=v"(Whi) : "v"(w0), "v"(w1));
        asm("v_cvt_pk_bf16_f32 %0, %1, %2" : "=v"(Wlo) : "v"(w0 - w0h), "v"(w1 - w1h));
        w_hi_s[e * 20 + q] = Whi;
        w_lo_s[e * 20 + q] = Wlo;
    }

    const float d = dist[(size_t)row * NN + j];

    // issue Pj loads early
    const float4* pj4 = reinterpret_cast<const float4*>(Pj + ((size_t)(b * NN + j)) * 32);
    float4 pj[8];
#pragma unroll
    for (int q = 0; q < 8; ++q) pj[q] = pj4[q];

    __syncthreads();   // albe + w_hi/w_lo ready

    // segment lookup
    int seg = 0;
#pragma unroll
    for (int k = 0; k < 16; ++k) seg += (d > bps[k]) ? 1 : 0;
    const float* ab = &albe[seg * 68];

    // pre[c] = Pi[row][c] + Pj[b,j][c] + d*alpha[c] + beta[c]
    const float* PiRow = Pi + (size_t)row * 32;    // uniform -> s_load
    float pre[32];
#pragma unroll
    for (int q = 0; q < 8; ++q) {
        const float4 al = *reinterpret_cast<const float4*>(&ab[q * 4]);
        const float4 be = *reinterpret_cast<const float4*>(&ab[32 + q * 4]);
        pre[q * 4 + 0] = PiRow[q * 4 + 0] + pj[q].x + fmaf(d, al.x, be.x);
        pre[q * 4 + 1] = PiRow[q * 4 + 1] + pj[q].y + fmaf(d, al.y, be.y);
        pre[q * 4 + 2] = PiRow[q * 4 + 2] + pj[q].z + fmaf(d, al.z, be.z);
        pre[q * 4 + 3] = PiRow[q * 4 + 3] + pj[q].w + fmaf(d, al.w, be.w);
    }

    // LayerNorm over 32 channels
    float s0 = 0.f, s1 = 0.f, s2 = 0.f, s3 = 0.f;
#pragma unroll
    for (int c = 0; c < 32; c += 4) { s0 += pre[c]; s1 += pre[c + 1]; s2 += pre[c + 2]; s3 += pre[c + 3]; }
    const float mu = ((s0 + s1) + (s2 + s3)) * (1.f / 32.f);
    float v0 = 0.f, v1 = 0.f, v2 = 0.f, v3 = 0.f;
#pragma unroll
    for (int c = 0; c < 32; c += 4) {
        pre[c]     -= mu; v0 = fmaf(pre[c],     pre[c],     v0);
        pre[c + 1] -= mu; v1 = fmaf(pre[c + 1], pre[c + 1], v1);
        pre[c + 2] -= mu; v2 = fmaf(pre[c + 2], pre[c + 2], v2);
        pre[c + 3] -= mu; v3 = fmaf(pre[c + 3], pre[c + 3], v3);
    }
    const float rstd = rsqrtf(fmaf((v0 + v1) + (v2 + v3), 1.f / 32.f, 1e-5f));

    // h[c] = relu(LN affine), in place
#pragma unroll
    for (int c = 0; c < 32; ++c)
        pre[c] = fmaxf(fmaf(pre[c] * rstd, ln_g[c], ln_b[c]), 0.f);

    // pack h to bf16 pairs -> LDS row j
    {
        uint hw[16];
#pragma unroll
        for (int q = 0; q < 16; ++q) {
            uint r;
            asm("v_cvt_pk_bf16_f32 %0, %1, %2" : "=v"(r) : "v"(pre[2 * q]), "v"(pre[2 * q + 1]));
            hw[q] = r;
        }
        uint* hrow = &h_lds[j * 20];
        *reinterpret_cast<uint4*>(hrow + 0)  = make_uint4(hw[0],  hw[1],  hw[2],  hw[3]);
        *reinterpret_cast<uint4*>(hrow + 4)  = make_uint4(hw[4],  hw[5],  hw[6],  hw[7]);
        *reinterpret_cast<uint4*>(hrow + 8)  = make_uint4(hw[8],  hw[9],  hw[10], hw[11]);
        *reinterpret_cast<uint4*>(hrow + 12) = make_uint4(hw[12], hw[13], hw[14], hw[15]);
    }
    // (intra-wave LDS RAW: compiler inserts lgkmcnt; no block barrier needed here)

    // ---- MFMA: D[e][edge] = uW2^T @ h, 4 tiles of 16 edges per wave ----
    const int lane = j & 63, wave = j >> 6;
    const int eRow = lane & 15;          // A row (e) / B col (edge-in-tile)
    const int g    = lane >> 4;          // k-group
    const bf16x8 ahi = *reinterpret_cast<const bf16x8*>(&w_hi_s[eRow * 20 + g * 4]);
    const bf16x8 alo = *reinterpret_cast<const bf16x8*>(&w_lo_s[eRow * 20 + g * 4]);
    const float4 ub2v = *reinterpret_cast<const float4*>(&ub2[g * 4]);
    const float scale = visited[row] ? 0.5f : 1.0f;    // uniform

    v4f accsum = {0.f, 0.f, 0.f, 0.f};
#pragma unroll
    for (int t = 0; t < 4; ++t) {
        const int edge = wave * 64 + t * 16 + eRow;
        const bf16x8 bfr = *reinterpret_cast<const bf16x8*>(&h_lds[edge * 20 + g * 4]);
        v4f acc = {ub2v.x, ub2v.y, ub2v.z, ub2v.w};
        acc = __builtin_amdgcn_mfma_f32_16x16x32_bf16(alo, bfr, acc, 0, 0, 0);
        acc = __builtin_amdgcn_mfma_f32_16x16x32_bf16(ahi, bfr, acc, 0, 0, 0);
        acc[0] *= scale; acc[1] *= scale; acc[2] *= scale; acc[3] *= scale;
        // lane holds D[e = g*4 + r][edge]; store 4 consecutive e -> dwordx4, wave covers 1KB
        *reinterpret_cast<v4f*>(ef_out + ((size_t)row * NN + edge) * 16 + g * 4) = acc;
        accsum += acc;
    }

    // pooled: sum over the wave's 64 edges (cols), then across waves
#pragma unroll
    for (int r = 0; r < 4; ++r) {
        float v = accsum[r];
        v += __shfl_xor(v, 1);
        v += __shfl_xor(v, 2);
        v += __shfl_xor(v, 4);
        v += __shfl_xor(v, 8);
        accsum[r] = v;
    }
    if (eRow == 0)
        *reinterpret_cast<v4f*>(&red2[wave][g * 4]) = accsum;
    __syncthreads();
    if (j < 16)
        pooled[(size_t)row * 16 + j] =
            (red2[0][j] + red2[1][j] + red2[2][j] + red2[3][j]) * (1.f / 256.f);
}

// ==================== node MLP =======================================================
__global__ __launch_bounds__(128) void k_node(
    const float* __restrict__ pooled,
    const float* __restrict__ nW1, const float* __restrict__ nb1,
    const float* __restrict__ nW2, const float* __restrict__ nb2,
    float* __restrict__ msg_out)
{
    const int row = blockIdx.x;           // b*N + n
    const int tid = threadIdx.x;          // 128 threads
    __shared__ float hid[64];
    __shared__ float prow[16];
    if (tid < 16) prow[tid] = pooled[(size_t)row * 16 + tid];
    __syncthreads();
    if (tid < 64) {
        float s = nb1[tid];
#pragma unroll
        for (int e = 0; e < 16; ++e)
            s = fmaf(prow[e], nW1[e * 64 + tid], s);
        hid[tid] = fmaxf(s, 0.f);
    }
    __syncthreads();
    float s = nb2[tid];
#pragma unroll 8
    for (int q = 0; q < 64; ++q)
        s = fmaf(hid[q], nW2[q * 128 + tid], s);
    msg_out[(size_t)row * 128 + tid] = s;
}

extern "C" void kernel_launch(void* const* d_in, const int* in_sizes, int n_in,
                              void* d_out, int out_size, void* d_ws, size_t ws_size,
                              hipStream_t stream)
{
    const float* node    = (const float*)d_in[0];
    const float* dist    = (const float*)d_in[1];
    const int*   visited = (const int*)  d_in[2];
    const float* dW1     = (const float*)d_in[3];
    const float* db1     = (const float*)d_in[4];
    const float* dW2     = (const float*)d_in[5];
    const float* db2     = (const float*)d_in[6];
    const float* uW1     = (const float*)d_in[7];
    const float* ub1     = (const float*)d_in[8];
    const float* ln_g    = (const float*)d_in[9];
    const float* ln_b    = (const float*)d_in[10];
    const float* uW2     = (const float*)d_in[11];
    const float* ub2     = (const float*)d_in[12];
    const float* nW1     = (const float*)d_in[13];
    const float* nb1     = (const float*)d_in[14];
    const float* nW2     = (const float*)d_in[15];
    const float* nb2     = (const float*)d_in[16];

    float* ws     = (float*)d_ws;
    float* bps    = ws;                    // 16
    float* albe   = ws + 16;               // 17*68 = 1156
    float* Pi     = ws + 16 + 1156;        // 4096*32
    float* Pj     = Pi + 4096 * 32;        // 4096*32
    float* pooled = Pj + 4096 * 32;        // 4096*16

    float* out = (float*)d_out;
    float* msg = out + EF_ELEMS;

    hipLaunchKernelGGL(k_prep2, dim3(1), dim3(576), 0, stream,
                       dW1, db1, dW2, db2, uW1, ub1, bps, albe);
    hipLaunchKernelGGL(k_proj, dim3(NB * NN), dim3(64), 0, stream, node, uW1, Pi, Pj);
    hipLaunchKernelGGL(k_edge3, dim3(NB * NN), dim3(256), 0, stream,
                       dist, visited, ln_g, ln_b, uW2, ub2, bps, albe, Pi, Pj, out, pooled);
    hipLaunchKernelGGL(k_node, dim3(NB * NN), dim3(128), 0, stream, pooled, nW1, nb1, nW2, nb2, msg);
}

// Round 6
// 40.778 us; speedup vs baseline: 2.5071x; 1.2787x over previous
//
#include <hip/hip_runtime.h>

#define NB 16
#define NN 256
#define NH 128
#define NE 16

typedef float v4f  __attribute__((ext_vector_type(4)));
typedef short bf16x8 __attribute__((ext_vector_type(8)));
typedef unsigned int uint;

constexpr long long EF_ELEMS = (long long)NB * NN * NN * NE; // 16777216

// ws layout (floats): bps[16] | albe[1280] | Pi[4096*32] | Pj[4096*32]

// ==================== A: fused prep (block 1024) + proj (blocks 0..1023) ============
__global__ __launch_bounds__(256) void k_prep_proj(
    const float* __restrict__ node, const float* __restrict__ uW1,
    const float* __restrict__ dW1, const float* __restrict__ db1,
    const float* __restrict__ dW2, const float* __restrict__ db2,
    const float* __restrict__ ub1,
    float* __restrict__ bps, float* __restrict__ albe,
    float* __restrict__ Pi, float* __restrict__ Pj)
{
    const int t = threadIdx.x;
    if (blockIdx.x == 1024) {
        // ---- prep: piecewise-linear fold of dist MLP into (alpha,beta) per segment
        __shared__ float sM[512];      // M[16][32] = dW2 @ uW1[256:,:]
        __shared__ float sBp[16];
        __shared__ float sA[16], sB[16];
        for (int i = t; i < 512; i += 256) {
            const int k = i >> 5, c = i & 31;
            float s = 0.f;
#pragma unroll
            for (int e = 0; e < 16; ++e)
                s = fmaf(dW2[k * 16 + e], uW1[(256 + e) * 32 + c], s);
            sM[i] = s;
        }
        if (t < 16) { sA[t] = dW1[t]; sB[t] = db1[t]; }
        __syncthreads();
        if (t < 16) {
            const float a = sA[t];
            const float x = (a != 0.f) ? (-sB[t] / a) : -1e30f;
            int r = 0;
            for (int q = 0; q < 16; ++q) {
                const float aq = sA[q];
                const float xq = (aq != 0.f) ? (-sB[q] / aq) : -1e30f;
                r += (xq < x) || (xq == x && q < t);
            }
            sBp[r] = x;
        }
        __syncthreads();
        if (t < 16) bps[t] = sBp[t];
        for (int i = t; i < 544; i += 256) {
            const int s = i >> 5, c = i & 31;
            float dt;
            if (s == 0)       dt = sBp[0] - 1.0f;
            else if (s == 16) dt = sBp[15] + 1.0f;
            else              dt = 0.5f * (sBp[s - 1] + sBp[s]);
            float alpha = 0.f, beta = 0.f;
#pragma unroll
            for (int k = 0; k < 16; ++k) {
                if (fmaf(sA[k], dt, sB[k]) > 0.f) {
                    const float m = sM[k * 32 + c];
                    alpha = fmaf(sA[k], m, alpha);
                    beta  = fmaf(sB[k], m, beta);
                }
            }
            float c2 = ub1[c];
#pragma unroll
            for (int e = 0; e < 16; ++e)
                c2 = fmaf(db2[e], uW1[(256 + e) * 32 + c], c2);
            albe[s * 68 + c]      = alpha;
            albe[s * 68 + 32 + c] = beta + c2;
        }
        for (int i = 1156 + t; i < 1280; i += 256) albe[i] = 0.f;  // pad for vec copy
    } else {
        // ---- proj: 4 rows per block; Pi = node@uW1[:128], Pj = node@uW1[128:256]
        const int r = t >> 6, sub = t & 63;
        const int row = blockIdx.x * 4 + r;
        __shared__ float nrow[4][128];
        nrow[r][sub]      = node[(size_t)row * 128 + sub];
        nrow[r][sub + 64] = node[(size_t)row * 128 + 64 + sub];
        __syncthreads();
        const int c = sub & 31;
        const int half = sub >> 5;        // 0 -> Pi, 1 -> Pj
        const float* w = uW1 + half * 128 * 32 + c;
        float s = 0.f;
#pragma unroll 8
        for (int k = 0; k < 128; ++k)
            s = fmaf(nrow[r][k], w[k * 32], s);
        (half ? Pj : Pi)[(size_t)row * 32 + c] = s;
    }
}

// ==================== B: edge (4 rows/block, MFMA epilogue) + node MLP ===============
__global__ __launch_bounds__(256) void k_edge4(
    const float* __restrict__ dist, const int* __restrict__ visited,
    const float* __restrict__ ln_g, const float* __restrict__ ln_b,
    const float* __restrict__ uW2, const float* __restrict__ ub2,
    const float* __restrict__ bps, const float* __restrict__ albe_g,
    const float* __restrict__ Pi, const float* __restrict__ Pj,
    const float* __restrict__ nW1, const float* __restrict__ nb1,
    const float* __restrict__ nW2, const float* __restrict__ nb2,
    float* __restrict__ ef_out, float* __restrict__ msg_out)
{
    const int row0 = blockIdx.x * 4;      // 4 rows, all in batch b
    const int b = row0 >> 8;
    const int j = threadIdx.x;

    __shared__ float albe_s[1280];        // 5120 B (68-stride seg table + pad)
    __shared__ uint  h_lds[256 * 20];     // 20480 B: [edge][16 bf16-pair dwords], pad 20
    __shared__ uint  w_hi_s[16 * 20];     // 1280 B
    __shared__ uint  w_lo_s[16 * 20];     // 1280 B
    __shared__ float red2[4][4][16];      // 1024 B: [row][wave][e]
    __shared__ float pool_s[4][16];       // 256 B
    __shared__ float hid_s[4][64];        // 1024 B

    // stage albe (vectorized 320 float4, 2 rounds)
    {
        const float4* ag = reinterpret_cast<const float4*>(albe_g);
        float4* as = reinterpret_cast<float4*>(albe_s);
        for (int q = j; q < 320; q += 256) as[q] = ag[q];
    }
    // stage uW2 as bf16 hi/lo split, A-layout [e][channel-pair dwords]
    {
        const int e = j & 15, q = j >> 4;   // q -> channels 2q, 2q+1
        const float w0 = uW2[(2 * q) * 16 + e];
        const float w1 = uW2[(2 * q + 1) * 16 + e];
        uint W00, W11, Whi, Wlo;
        asm("v_cvt_pk_bf16_f32 %0, %1, %2" : "=v"(W00) : "v"(w0), "v"(w0));
        asm("v_cvt_pk_bf16_f32 %0, %1, %2" : "=v"(W11) : "v"(w1), "v"(w1));
        const float w0h = __uint_as_float(W00 << 16);
        const float w1h = __uint_as_float(W11 << 16);
        asm("v_cvt_pk_bf16_f32 %0, %1, %2" : "=v"(Whi) : "v"(w0), "v"(w1));
        asm("v_cvt_pk_bf16_f32 %0, %1, %2" : "=v"(Wlo) : "v"(w0 - w0h), "v"(w1 - w1h));
        w_hi_s[e * 20 + q] = Whi;
        w_lo_s[e * 20 + q] = Wlo;
    }

    // preload the 4 dists (coalesced per row)
    float dq[4];
#pragma unroll
    for (int r = 0; r < 4; ++r)
        dq[r] = dist[(size_t)(row0 + r) * NN + j];

    __syncthreads();   // albe_s + w_hi/w_lo ready

    const int lane = j & 63, wv = j >> 6;
    const int eRow = lane & 15;           // A row (e) / B col (edge-in-tile)
    const int g    = lane >> 4;           // k-group
    const bf16x8 ahi = *reinterpret_cast<const bf16x8*>(&w_hi_s[eRow * 20 + g * 4]);
    const bf16x8 alo = *reinterpret_cast<const bf16x8*>(&w_lo_s[eRow * 20 + g * 4]);
    const float4 ub2v = *reinterpret_cast<const float4*>(&ub2[g * 4]);
    const float4* pj4 = reinterpret_cast<const float4*>(Pj + ((size_t)(b * NN + j)) * 32);

#pragma unroll
    for (int r = 0; r < 4; ++r) {
        const int row = row0 + r;
        const float d = dq[r];

        // segment lookup
        int seg = 0;
#pragma unroll
        for (int k = 0; k < 16; ++k) seg += (d > bps[k]) ? 1 : 0;
        const float* ab = &albe_s[seg * 68];

        // pre[c] = Pi[row][c] + Pj[b,j][c] + d*alpha[c] + beta[c]
        const float* PiRow = Pi + (size_t)row * 32;   // uniform -> s_load
        float pre[32];
#pragma unroll
        for (int q = 0; q < 8; ++q) {
            const float4 pv = pj4[q];                 // L1-hit on r>0
            const float4 al = *reinterpret_cast<const float4*>(&ab[q * 4]);
            const float4 be = *reinterpret_cast<const float4*>(&ab[32 + q * 4]);
            pre[q * 4 + 0] = PiRow[q * 4 + 0] + pv.x + fmaf(d, al.x, be.x);
            pre[q * 4 + 1] = PiRow[q * 4 + 1] + pv.y + fmaf(d, al.y, be.y);
            pre[q * 4 + 2] = PiRow[q * 4 + 2] + pv.z + fmaf(d, al.z, be.z);
            pre[q * 4 + 3] = PiRow[q * 4 + 3] + pv.w + fmaf(d, al.w, be.w);
        }

        // LayerNorm over 32 channels
        float s0 = 0.f, s1 = 0.f, s2 = 0.f, s3 = 0.f;
#pragma unroll
        for (int c = 0; c < 32; c += 4) { s0 += pre[c]; s1 += pre[c+1]; s2 += pre[c+2]; s3 += pre[c+3]; }
        const float mu = ((s0 + s1) + (s2 + s3)) * (1.f / 32.f);
        float v0 = 0.f, v1 = 0.f, v2 = 0.f, v3 = 0.f;
#pragma unroll
        for (int c = 0; c < 32; c += 4) {
            pre[c]   -= mu; v0 = fmaf(pre[c],   pre[c],   v0);
            pre[c+1] -= mu; v1 = fmaf(pre[c+1], pre[c+1], v1);
            pre[c+2] -= mu; v2 = fmaf(pre[c+2], pre[c+2], v2);
            pre[c+3] -= mu; v3 = fmaf(pre[c+3], pre[c+3], v3);
        }
        const float rstd = rsqrtf(fmaf((v0 + v1) + (v2 + v3), 1.f / 32.f, 1e-5f));

        // h = relu(LN affine); pack to bf16 pairs -> LDS row j (wave-local buffer)
#pragma unroll
        for (int c = 0; c < 32; ++c)
            pre[c] = fmaxf(fmaf(pre[c] * rstd, ln_g[c], ln_b[c]), 0.f);
        {
            uint hw[16];
#pragma unroll
            for (int q = 0; q < 16; ++q) {
                uint rr;
                asm("v_cvt_pk_bf16_f32 %0, %1, %2" : "=v"(rr) : "v"(pre[2*q]), "v"(pre[2*q+1]));
                hw[q] = rr;
            }
            uint* hrow = &h_lds[j * 20];
            *reinterpret_cast<uint4*>(hrow + 0)  = make_uint4(hw[0],  hw[1],  hw[2],  hw[3]);
            *reinterpret_cast<uint4*>(hrow + 4)  = make_uint4(hw[4],  hw[5],  hw[6],  hw[7]);
            *reinterpret_cast<uint4*>(hrow + 8)  = make_uint4(hw[8],  hw[9],  hw[10], hw[11]);
            *reinterpret_cast<uint4*>(hrow + 12) = make_uint4(hw[12], hw[13], hw[14], hw[15]);
        }
        // (same-wave DS ordering: each wave reads only its own 64 rows of h_lds)

        const float scale = visited[row] ? 0.5f : 1.0f;   // uniform
        v4f accsum = {0.f, 0.f, 0.f, 0.f};
#pragma unroll
        for (int t = 0; t < 4; ++t) {
            const int edge = wv * 64 + t * 16 + eRow;
            const bf16x8 bfr = *reinterpret_cast<const bf16x8*>(&h_lds[edge * 20 + g * 4]);
            v4f acc = {ub2v.x, ub2v.y, ub2v.z, ub2v.w};
            acc = __builtin_amdgcn_mfma_f32_16x16x32_bf16(alo, bfr, acc, 0, 0, 0);
            acc = __builtin_amdgcn_mfma_f32_16x16x32_bf16(ahi, bfr, acc, 0, 0, 0);
            acc[0] *= scale; acc[1] *= scale; acc[2] *= scale; acc[3] *= scale;
            *reinterpret_cast<v4f*>(ef_out + ((size_t)row * NN + edge) * 16 + g * 4) = acc;
            accsum += acc;
        }
#pragma unroll
        for (int rr = 0; rr < 4; ++rr) {
            float v = accsum[rr];
            v += __shfl_xor(v, 1);
            v += __shfl_xor(v, 2);
            v += __shfl_xor(v, 4);
            v += __shfl_xor(v, 8);
            accsum[rr] = v;
        }
        if (eRow == 0)
            *reinterpret_cast<v4f*>(&red2[r][wv][g * 4]) = accsum;
    }

    __syncthreads();   // red2 complete for all 4 rows

    // pooled means
    if (j < 64) {
        const int r = j >> 4, e = j & 15;
        pool_s[r][e] = (red2[r][0][e] + red2[r][1][e] + red2[r][2][e] + red2[r][3][e])
                       * (1.f / 256.f);
    }
    __syncthreads();

    // node MLP layer 1: hid[r][u] = relu(pool[r] @ nW1 + nb1)
    {
        const int r = j >> 6, u = j & 63;
        float s = nb1[u];
#pragma unroll
        for (int e = 0; e < 16; ++e)
            s = fmaf(pool_s[r][e], nW1[e * 64 + u], s);
        hid_s[r][u] = fmaxf(s, 0.f);
    }
    __syncthreads();

    // node MLP layer 2: msg[r][o] = hid[r] @ nW2 + nb2  (512 outputs, 2 passes)
#pragma unroll
    for (int p = 0; p < 2; ++p) {
        const int idx = p * 256 + j;
        const int r = idx >> 7, o = idx & 127;
        float s = nb2[o];
#pragma unroll 8
        for (int q = 0; q < 64; ++q)
            s = fmaf(hid_s[r][q], nW2[q * 128 + o], s);
        msg_out[(size_t)(row0 + r) * 128 + o] = s;
    }
}

extern "C" void kernel_launch(void* const* d_in, const int* in_sizes, int n_in,
                              void* d_out, int out_size, void* d_ws, size_t ws_size,
                              hipStream_t stream)
{
    const float* node    = (const float*)d_in[0];
    const float* dist    = (const float*)d_in[1];
    const int*   visited = (const int*)  d_in[2];
    const float* dW1     = (const float*)d_in[3];
    const float* db1     = (const float*)d_in[4];
    const float* dW2     = (const float*)d_in[5];
    const float* db2     = (const float*)d_in[6];
    const float* uW1     = (const float*)d_in[7];
    const float* ub1     = (const float*)d_in[8];
    const float* ln_g    = (const float*)d_in[9];
    const float* ln_b    = (const float*)d_in[10];
    const float* uW2     = (const float*)d_in[11];
    const float* ub2     = (const float*)d_in[12];
    const float* nW1     = (const float*)d_in[13];
    const float* nb1     = (const float*)d_in[14];
    const float* nW2     = (const float*)d_in[15];
    const float* nb2     = (const float*)d_in[16];

    float* ws   = (float*)d_ws;
    float* bps  = ws;                    // 16
    float* albe = ws + 16;               // 1280 (1156 used + pad)
    float* Pi   = ws + 16 + 1280;        // 4096*32
    float* Pj   = Pi + 4096 * 32;        // 4096*32

    float* out = (float*)d_out;
    float* msg = out + EF_ELEMS;

    hipLaunchKernelGGL(k_prep_proj, dim3(1025), dim3(256), 0, stream,
                       node, uW1, dW1, db1, dW2, db2, ub1, bps, albe, Pi, Pj);
    hipLaunchKernelGGL(k_edge4, dim3(1024), dim3(256), 0, stream,
                       dist, visited, ln_g, ln_b, uW2, ub2, bps, albe, Pi, Pj,
                       nW1, nb1, nW2, nb2, out, msg);
}